// Round 3
// baseline (237.619 us; speedup 1.0000x reference)
//
#include <hip/hip_runtime.h>

#define S_LEN 512
#define H_DIM 128
#define C_DIM 10

typedef __attribute__((ext_vector_type(8))) short short8;
typedef __attribute__((ext_vector_type(4))) float f32x4;

__device__ __forceinline__ unsigned short f2bf(float f) {
    union { float f; unsigned u; } v; v.f = f;
    return (unsigned short)((v.u + 0x7FFFu + ((v.u >> 16) & 1u)) >> 16);
}

__device__ __forceinline__ float fast_sigmoid(float x) {
    float e = __builtin_amdgcn_exp2f(-1.4426950408889634f * x);
    return __builtin_amdgcn_rcpf(1.0f + e);
}
__device__ __forceinline__ float fast_tanh(float x) {
    float e = __builtin_amdgcn_exp2f(2.8853900817779268f * x);  // e^{2x}
    return 1.0f - 2.0f * __builtin_amdgcn_rcpf(e + 1.0f);
}

// 256 blocks x 512 threads (8 waves), 4 batch rows/block at MFMA M-rows 4b.
// h is stored in LDS in A-FRAGMENT ORDER: hb[buf][kk][kg2][r][e] (bf16),
// so the 16 active lanes (lane%4==0, q=lane/4) read 16 consecutive 16B
// chunks per kk -> conflict-free ds_read_b128. h-writes are packed pairs
// (shfl_xor + v_cvt_pk_bf16_f32): 32 lanes x 1 dword = 32 banks, no
// conflict. x is read as f32x4 broadcast once per 4 steps from padded
// xr[4][516]. Wh lives in registers (bf16 B-fragments) all kernel.
// MFMA per gate split into two 2-deep chains to halve dependent latency.
__global__ __launch_bounds__(512, 2) void lstm_fused(
    const float* __restrict__ x,
    const float* __restrict__ Wgx, const float* __restrict__ Wgh,
    const float* __restrict__ Wix, const float* __restrict__ Wih,
    const float* __restrict__ Wfx, const float* __restrict__ Wfh,
    const float* __restrict__ Wox, const float* __restrict__ Woh,
    const float* __restrict__ Wph,
    const float* __restrict__ bg, const float* __restrict__ bi,
    const float* __restrict__ bff, const float* __restrict__ bo,
    const float* __restrict__ bp,
    float* __restrict__ out)
{
    __shared__ float xr[4][516];                                      // pad: kg rows bank-shifted
    __shared__ __attribute__((aligned(16))) unsigned short hb[2][512]; // A-frag order, 1KB/buf
    __shared__ float hfin[4][H_DIM];

    const int tid  = threadIdx.x;
    const int lane = tid & 63;
    const int w    = tid >> 6;        // wave 0..7
    const int b0   = blockIdx.x * 4;  // batch row base

    // ---- stage x (coalesced global, conflict-free LDS writes) ----
    {
        const float* xp = x + b0 * S_LEN + tid;
        #pragma unroll
        for (int r = 0; r < 4; ++r) xr[r][tid] = xp[r * S_LEN];
    }
    ((unsigned short*)hb)[tid] = 0;   // zero hb[0] (512 ushorts)

    const int jl = lane & 15;   // col within 16-wide tile
    const int kg = lane >> 4;   // 0..3
    const int j  = w * 16 + jl; // h-column 0..127 owned by this lane

    // ---- Wh into registers as B-fragments: B[k][n=j], bf16 ----
    const float* WhA[4] = { Wgh, Wih, Wfh, Woh };
    short8 bfrag[4][4];
    #pragma unroll
    for (int g = 0; g < 4; ++g) {
        #pragma unroll
        for (int kk = 0; kk < 4; ++kk) {
            const float* src = WhA[g] + (kk * 32 + kg * 8) * H_DIM + j;
            short8 v;
            #pragma unroll
            for (int e = 0; e < 8; ++e) v[e] = (short)f2bf(src[e * H_DIM]);
            bfrag[g][kk] = v;
        }
    }
    const float wxv[4] = { Wgx[j], Wix[j], Wfx[j], Wox[j] };
    const float bv[4]  = { bg[j],  bi[j],  bff[j], bo[j]  };

    // A-frag read: lane 4q needs h[batch q&3][32kk + 8*(q>>2) + e]
    // layout offset = kk*256 + (q>>2)*64 + (q&3)*16 = kk*256 + q*16
    const bool aActive = (lane & 3) == 0;
    const int  abase   = (lane >> 2) * 16;          // + kk*256

    // h write: even-j lanes write dword {h[j], h[j+1]}
    // byte = (j>>5)*256 + ((j>>3)&3)*64 + kg*16 + (j&7)*2
    const bool wActive = (jl & 1) == 0;
    const int  wbyte   = (j >> 5) * 256 + ((j >> 3) & 3) * 64 + kg * 16 + (j & 7) * 2;

    float cst  = 0.f;
    float hcur = 0.f;

    short8 afr[4];
    #pragma unroll
    for (int kk = 0; kk < 4; ++kk) afr[kk] = short8{0,0,0,0,0,0,0,0};

    __syncthreads();

    auto step = [&](const unsigned short* src, unsigned short* dst, float xv) {
        if (aActive) {
            const char* base = (const char*)src + abase;
            #pragma unroll
            for (int kk = 0; kk < 4; ++kk)
                afr[kk] = *(const short8*)(base + kk * 256);
        }
        f32x4 a0[4] = {}, a1[4] = {};
        #pragma unroll
        for (int g = 0; g < 4; ++g) {
            a0[g] = __builtin_amdgcn_mfma_f32_16x16x32_bf16(afr[0], bfrag[g][0], a0[g], 0, 0, 0);
            a1[g] = __builtin_amdgcn_mfma_f32_16x16x32_bf16(afr[2], bfrag[g][2], a1[g], 0, 0, 0);
            a0[g] = __builtin_amdgcn_mfma_f32_16x16x32_bf16(afr[1], bfrag[g][1], a0[g], 0, 0, 0);
            a1[g] = __builtin_amdgcn_mfma_f32_16x16x32_bf16(afr[3], bfrag[g][3], a1[g], 0, 0, 0);
        }
        const float pg = a0[0][0] + a1[0][0] + xv * wxv[0] + bv[0];
        const float pi = a0[1][0] + a1[1][0] + xv * wxv[1] + bv[1];
        const float pf = a0[2][0] + a1[2][0] + xv * wxv[2] + bv[2];
        const float po = a0[3][0] + a1[3][0] + xv * wxv[3] + bv[3];
        const float cn = fast_tanh(pg) * fast_sigmoid(pi) + cst * fast_sigmoid(pf);
        cst  = cn;
        hcur = fast_tanh(cn) * fast_sigmoid(po);
        const float hnb = __shfl_xor(hcur, 1);  // neighbor column j^1
        if (wActive) {
            unsigned pk;
            asm("v_cvt_pk_bf16_f32 %0, %1, %2" : "=v"(pk) : "v"(hcur), "v"(hnb));
            *(unsigned*)((char*)dst + wbyte) = pk;
        }
        __syncthreads();
    };

    unsigned short* h0 = &hb[0][0];
    unsigned short* h1 = &hb[1][0];
    for (int t = 0; t < S_LEN; t += 4) {
        const f32x4 xq = *(const f32x4*)&xr[kg][t];
        step(h0, h1, xq[0]);
        step(h1, h0, xq[1]);
        step(h0, h1, xq[2]);
        step(h1, h0, xq[3]);
    }

    // ---- epilogue: logits = h_last @ W_ph + b_p ----
    hfin[kg][j] = hcur;
    __syncthreads();

    if (tid < 4 * C_DIM) {
        const int b = tid / C_DIM, cc = tid % C_DIM;
        float s = bp[cc];
        #pragma unroll 4
        for (int k = 0; k < H_DIM; ++k) s += hfin[b][k] * Wph[k * C_DIM + cc];
        out[(b0 + b) * C_DIM + cc] = s;
    }
}

extern "C" void kernel_launch(void* const* d_in, const int* in_sizes, int n_in,
                              void* d_out, int out_size, void* d_ws, size_t ws_size,
                              hipStream_t stream) {
    const float* x   = (const float*)d_in[0];
    const float* Wgx = (const float*)d_in[1];
    const float* Wgh = (const float*)d_in[2];
    const float* Wix = (const float*)d_in[3];
    const float* Wih = (const float*)d_in[4];
    const float* Wfx = (const float*)d_in[5];
    const float* Wfh = (const float*)d_in[6];
    const float* Wox = (const float*)d_in[7];
    const float* Woh = (const float*)d_in[8];
    const float* Wph = (const float*)d_in[9];
    const float* bg  = (const float*)d_in[10];
    const float* bi  = (const float*)d_in[11];
    const float* bf  = (const float*)d_in[12];
    const float* bo  = (const float*)d_in[13];
    const float* bp  = (const float*)d_in[14];
    float* out = (float*)d_out;

    lstm_fused<<<dim3(256), dim3(512), 0, stream>>>(
        x, Wgx, Wgh, Wix, Wih, Wfx, Wfh, Wox, Woh, Wph,
        bg, bi, bf, bo, bp, out);
}